// Round 1
// baseline (374.063 us; speedup 1.0000x reference)
//
#include <hip/hip_runtime.h>

#define NEG (-1e9f)
constexpr int NCLS   = 21;
constexpr int NBOX   = 8732;
constexpr int MAXOUT = 5;
constexpr int CAP    = NBOX;          // worst-case candidates per batch
constexpr float IOU_THR  = 0.5f;
constexpr float CONF_THR = 0.5f;

constexpr int TPB             = 128;
constexpr int BOXES_PER_BLOCK = TPB * 4;                                   // 512
constexpr int BPB             = (NBOX + BOXES_PER_BLOCK - 1) / BOXES_PER_BLOCK; // 18

// ---------------------------------------------------------------------------
// Fused kernel: decode + candidate compaction + last-block-done NMS.
// Grid is organized per-batch: blockIdx.x = b*BPB + blk, each block covers 512
// consecutive boxes of ONE batch (NBOX%4==0 -> every 4-box group is a whole,
// 400B-aligned float4 run; no tail path needed). After a block finishes its
// boxes it releases its candidate writes (__threadfence) and bumps done[b];
// the 18th block for batch b acquires and runs the proven one-wave NMS
// inline. This removes the separate nms_kernel dispatch and overlaps NMS of
// early batches with decode of later ones (decoupled-lookback protocol:
// plain stores -> threadfence -> device-scope atomic -> threadfence -> read).
// Per-box arithmetic is IDENTICAL to the verified R5 kernel (bit-exact,
// absmax 0.0 across all prior rounds).
// ---------------------------------------------------------------------------
__device__ __forceinline__ void process_box(
        const float* __restrict__ v,   // 25 floats for this box (registers)
        int b, int n,
        const float4* __restrict__ dbox4,
        float4* __restrict__ cand,
        int* __restrict__ cnt) {
    // decode (identical expression order to reference)
    float4 db = dbox4[n];
    float cy = (db.z + db.x) * 0.5f;
    float cx = (db.w + db.y) * 0.5f;
    float h  = db.z - db.x;
    float w  = db.w - db.y;
    float ncy = v[0] * h + cy;
    float ncx = v[1] * w + cx;
    float nh  = expf(v[2]) * h;
    float nw  = expf(v[3]) * w;
    float y1 = fminf(fmaxf(ncy - nh * 0.5f, 0.f), 1.f);
    float x1 = fminf(fmaxf(ncx - nw * 0.5f, 0.f), 1.f);
    float y2 = fminf(fmaxf(ncy + nh * 0.5f, 0.f), 1.f);
    float x2 = fminf(fmaxf(ncx + nw * 0.5f, 0.f), 1.f);

    // argmax(probs)==argmax(logits), first index on ties;
    // max prob = 1/sum(exp(x-max)), same accumulation order as reference
    float m = v[4];
    int am = 0;
#pragma unroll
    for (int j = 1; j < NCLS; j++) {
        float x = v[4 + j];
        if (x > m) { m = x; am = j; }
    }
    float sum = 0.f;
#pragma unroll
    for (int j = 0; j < NCLS; j++) sum += expf(v[4 + j] - m);
    float score = 1.0f / sum;

    if (am != 0 && score > CONF_THR) {
        int p = atomicAdd(&cnt[b], 1);
        if (p < CAP) {
            float4* c = cand + ((long long)b * CAP + p) * 2;
            c[0] = make_float4(y1, x1, y2, x2);
            c[1] = make_float4(score, (float)am, (float)n, 0.f);
        }
    }
}

__global__ __launch_bounds__(TPB) void fused_kernel(
        const float* __restrict__ logits,
        const float4* __restrict__ dbox4,
        float4* __restrict__ cand,
        int* __restrict__ cnt,
        int* __restrict__ done,
        float* __restrict__ out) {
    const int b   = blockIdx.x / BPB;
    const int blk = blockIdx.x % BPB;
    const int n0  = blk * BOXES_PER_BLOCK + threadIdx.x * 4;  // box idx within batch

    __shared__ float s_sc[CAP];
    __shared__ float s_id[CAP];
    __shared__ int   s_last;

    // ---- decode phase -----------------------------------------------------
    if (n0 < NBOX) {
        // NBOX % 4 == 0 -> full aligned 4-box group guaranteed (no tail path)
        const float4* f4 =
            (const float4*)(logits + ((long long)b * NBOX + n0) * 25);
        float v[100];
#pragma unroll
        for (int k = 0; k < 25; k++) {
            float4 r = f4[k];
            v[4 * k + 0] = r.x; v[4 * k + 1] = r.y;
            v[4 * k + 2] = r.z; v[4 * k + 3] = r.w;
        }
#pragma unroll
        for (int j = 0; j < 4; j++)
            process_box(v + 25 * j, b, n0 + j, dbox4, cand, cnt);
    }

    // ---- completion protocol (decoupled-lookback style) -------------------
    __threadfence();                 // release: candidate stores visible device-wide
    __syncthreads();                 // all lanes' stores + fences done
    if (threadIdx.x == 0)
        s_last = (atomicAdd(&done[b], 1) == BPB - 1);
    __syncthreads();
    if (!s_last) return;             // not the last block for this batch
    if (threadIdx.x >= 64) return;   // NMS = exactly one wave (proven R5 code)
    __threadfence();                 // acquire: invalidate caches before reads

    // ---- NMS phase (verbatim R5: single-owner s_sc, shuffle-only reduce) --
    const int lane = threadIdx.x;
    const int M = min(cnt[b], CAP);
    const float4* cb = cand + (long long)b * CAP * 2;
    float* o = out + (long long)b * MAXOUT * 6;

    for (int i = lane; i < M; i += 64) {
        float4 mrec = cb[i * 2 + 1];
        s_sc[i] = mrec.x;               // owner: lane i%64 == lane
        s_id[i] = mrec.z;
    }

    int k = 0;
    for (; k < MAXOUT; k++) {
        float bv = -INFINITY, boid = 3.0e38f;
        int bi = -1;
        for (int i = lane; i < M; i += 64) {
            float v = s_sc[i], oid = s_id[i];
            if (v > bv || (v == bv && oid < boid)) { bv = v; boid = oid; bi = i; }
        }
        for (int mm = 32; mm >= 1; mm >>= 1) {
            float v2 = __shfl_xor(bv,   mm, 64);
            float o2 = __shfl_xor(boid, mm, 64);
            int   i2 = __shfl_xor(bi,   mm, 64);
            if (v2 > bv || (v2 == bv && o2 < boid)) { bv = v2; boid = o2; bi = i2; }
        }
        if (bi < 0 || !(bv > CONF_THR)) break;   // this & later slots -> zeros

        float4 sb = cb[bi * 2];
        if (lane == 0) {
            float4 mm2 = cb[bi * 2 + 1];
            o[k * 6 + 0] = sb.x; o[k * 6 + 1] = sb.y;
            o[k * 6 + 2] = sb.z; o[k * 6 + 3] = sb.w;
            o[k * 6 + 4] = mm2.y; o[k * 6 + 5] = bv;
        }

        float a1 = (sb.z - sb.x) * (sb.w - sb.y);
        for (int i = lane; i < M; i += 64) {
            float4 c = cb[i * 2];
            float tly = fmaxf(sb.x, c.x);
            float tlx = fmaxf(sb.y, c.y);
            float bry = fminf(sb.z, c.z);
            float brx = fminf(sb.w, c.w);
            float wh0 = fmaxf(bry - tly, 0.f);
            float wh1 = fmaxf(brx - tlx, 0.f);
            float inter = wh0 * wh1;
            float a2 = (c.z - c.x) * (c.w - c.y);
            float iou = inter / (a1 + a2 - inter + 1e-12f);
            if (iou > IOU_THR) s_sc[i] = NEG;    // owner-only write
        }
    }
    for (int j = k * 6 + lane; j < MAXOUT * 6; j += 64) o[j] = 0.f;
}

extern "C" void kernel_launch(void* const* d_in, const int* in_sizes, int n_in,
                              void* d_out, int out_size, void* d_ws, size_t ws_size,
                              hipStream_t stream) {
    const float* logits = (const float*)d_in[0];
    const float4* dbox4 = (const float4*)d_in[1];
    float* out          = (float*)d_out;

    const int N = in_sizes[1] / 4;            // 8732
    const int B = in_sizes[0] / (N * 25);     // 128

    // ws layout: [cnt: B ints][done: B ints][pad to 16B][cand: B*CAP*2 float4]
    int* cnt  = (int*)d_ws;
    int* done = cnt + B;
    float4* cand = (float4*)((char*)d_ws +
        ((2 * (size_t)B * sizeof(int) + 15) & ~(size_t)15));

    hipMemsetAsync(d_ws, 0, 2 * (size_t)B * sizeof(int), stream);
    fused_kernel<<<B * BPB, TPB, 0, stream>>>(logits, dbox4, cand, cnt, done, out);
}